// Round 14
// baseline (317.201 us; speedup 1.0000x reference)
//
#include <hip/hip_runtime.h>
#include <hip/hip_bf16.h>

// GAT layer — r9 structure (best: 130.4 us) with k_att REP=4 DIAGNOSTIC loop:
// k_att repeats its full k-loop 4x (idempotent att rewrites, acc re-zeroed,
// part stored once) so the dispatch exceeds the harness fills (~160 us) and
// surfaces in rocprof top-5 with full counters. Next round reverts REP=1.

typedef __attribute__((ext_vector_type(4))) float f32x4;
typedef __attribute__((ext_vector_type(8))) short short8;
typedef __attribute__((ext_vector_type(4))) unsigned short ushort4v;

#define SLOPE 0.1f
#define NROW 8192
#define DDIM 256

__device__ __forceinline__ float lrelu(float x){ return fmaxf(x, SLOPE * x); }

__device__ __forceinline__ unsigned short f2bf(float f){
  union { float f; unsigned u; } v; v.f = f;
  unsigned r = (v.u + 0x7fffu + ((v.u >> 16) & 1u)) >> 16;
  return (unsigned short)r;
}
__device__ __forceinline__ float bf2f(unsigned short u){
  union { unsigned u; float f; } v; v.u = (unsigned)u << 16; return v.f;
}
__device__ __forceinline__ unsigned cvt_pk_bf16(float lo, float hi){
  unsigned r;
  asm("v_cvt_pk_bf16_f32 %0, %1, %2" : "=v"(r) : "v"(lo), "v"(hi));
  return r;
}

// ---------------- K0: Wt_hi/Wt_lo [256][512] bf16 split-transpose of W ----------------
__global__ __launch_bounds__(256) void k_prep(
    const float* __restrict__ W,
    unsigned short* __restrict__ Wt_hi, unsigned short* __restrict__ Wt_lo)
{
  const int tid = blockIdx.x * 256 + threadIdx.x;   // 32768 total
  const int c = tid >> 7, kq = tid & 127;
  ushort4v hi, lo;
#pragma unroll
  for (int j = 0; j < 4; ++j) {
    const float v = W[(size_t)(kq * 4 + j) * 256 + c];
    hi[j] = f2bf(v);
    lo[j] = f2bf(v - bf2f(hi[j]));
  }
  *reinterpret_cast<ushort4v*>(Wt_hi + (size_t)c * 512 + kq * 4) = hi;
  *reinterpret_cast<ushort4v*>(Wt_lo + (size_t)c * 512 + kq * 4) = lo;
}

// ---------------- K1: h-tile via split MFMA; fused s1/s2/e2/e02 + ht bf16 ----------------
__global__ __launch_bounds__(512, 2) void k_h(
    const float* __restrict__ doc, const unsigned short* __restrict__ Wt_hi,
    const unsigned short* __restrict__ Wt_lo, const float* __restrict__ Wb,
    const float* __restrict__ a,
    unsigned short* __restrict__ ht, float* __restrict__ s1,
    float* __restrict__ e2, float* __restrict__ e02)
{
  __shared__ __align__(16) short8 aH[2][2][64];
  __shared__ __align__(16) short8 aL[2][2][64];
  __shared__ float sred[8][2][32];

  const int t = threadIdx.x, w = t >> 6, l = t & 63;
  const int lr = l & 15, lg = l >> 4;
  const int rb = blockIdx.x * 32;
  const int cb = w * 32;

  f32x4 acc[2][2];
#pragma unroll
  for (int rt = 0; rt < 2; ++rt)
#pragma unroll
    for (int ct = 0; ct < 2; ++ct) acc[rt][ct] = (f32x4){0.f, 0.f, 0.f, 0.f};

  const float* docp = doc + (size_t)(rb + w * 16 + lr) * 512 + lg * 8;  // valid for w<2

  f32x4 v0, v1;
  auto loadDoc = [&](int k0) { if (w < 2) {
      v0 = *reinterpret_cast<const f32x4*>(docp + k0);
      v1 = *reinterpret_cast<const f32x4*>(docp + k0 + 4);
  }};
  auto writeStage = [&](int pb) { if (w < 2) {
      union { short8 v; unsigned short u[8]; } hi, lo;
#pragma unroll
      for (int q = 0; q < 4; ++q) {
        hi.u[q] = f2bf(v0[q]);     lo.u[q] = f2bf(v0[q] - bf2f(hi.u[q]));
        hi.u[4+q] = f2bf(v1[q]);   lo.u[4+q] = f2bf(v1[q] - bf2f(hi.u[4+q]));
      }
      aH[pb][w][l] = hi.v;
      aL[pb][w][l] = lo.v;
  }};

  loadDoc(0); writeStage(0); loadDoc(32);

  for (int n = 0; n < 16; ++n) {
    const int kk = n * 32;
    const int par = n & 1;

    asm volatile("s_waitcnt lgkmcnt(0)\n\ts_barrier" ::: "memory");

    const short8 ah0 = aH[par][0][l];
    const short8 ah1 = aH[par][1][l];
    const short8 al0 = aL[par][0][l];
    const short8 al1 = aL[par][1][l];

    short8 bh[2], bl[2];
#pragma unroll
    for (int ct = 0; ct < 2; ++ct) {
      const size_t off = (size_t)(cb + ct * 16 + lr) * 512 + kk + lg * 8;
      bh[ct] = *reinterpret_cast<const short8*>(Wt_hi + off);
      bl[ct] = *reinterpret_cast<const short8*>(Wt_lo + off);
    }

    if (n + 1 < 16) writeStage(par ^ 1);
    if (n + 2 < 16) loadDoc((n + 2) * 32);

#pragma unroll
    for (int ct = 0; ct < 2; ++ct) {
      acc[0][ct] = __builtin_amdgcn_mfma_f32_16x16x32_bf16(ah0, bh[ct], acc[0][ct], 0, 0, 0);
      acc[1][ct] = __builtin_amdgcn_mfma_f32_16x16x32_bf16(ah1, bh[ct], acc[1][ct], 0, 0, 0);
      acc[0][ct] = __builtin_amdgcn_mfma_f32_16x16x32_bf16(ah0, bl[ct], acc[0][ct], 0, 0, 0);
      acc[1][ct] = __builtin_amdgcn_mfma_f32_16x16x32_bf16(ah1, bl[ct], acc[1][ct], 0, 0, 0);
      acc[0][ct] = __builtin_amdgcn_mfma_f32_16x16x32_bf16(al0, bh[ct], acc[0][ct], 0, 0, 0);
      acc[1][ct] = __builtin_amdgcn_mfma_f32_16x16x32_bf16(al1, bh[ct], acc[1][ct], 0, 0, 0);
    }
  }

  float bias[2];
#pragma unroll
  for (int ct = 0; ct < 2; ++ct) bias[ct] = Wb[cb + ct * 16 + lr];
#pragma unroll
  for (int rt = 0; rt < 2; ++rt)
#pragma unroll
    for (int ct = 0; ct < 2; ++ct) {
#pragma unroll
      for (int q = 0; q < 4; ++q) acc[rt][ct][q] += bias[ct];
      ushort4v u;
#pragma unroll
      for (int q = 0; q < 4; ++q) u[q] = f2bf(acc[rt][ct][q]);
      *reinterpret_cast<ushort4v*>(
          ht + (size_t)(cb + ct * 16 + lr) * 8192 + rb + rt * 16 + lg * 4) = u;
    }

  float a1c[2], a2c[2];
#pragma unroll
  for (int ct = 0; ct < 2; ++ct) {
    a1c[ct] = a[cb + ct * 16 + lr];
    a2c[ct] = a[256 + cb + ct * 16 + lr];
  }
  float p1[2][4], p2[2][4];
#pragma unroll
  for (int rt = 0; rt < 2; ++rt)
#pragma unroll
    for (int q = 0; q < 4; ++q) {
      float x1 = 0.f, x2 = 0.f;
#pragma unroll
      for (int ct = 0; ct < 2; ++ct) {
        x1 = fmaf(acc[rt][ct][q], a1c[ct], x1);
        x2 = fmaf(acc[rt][ct][q], a2c[ct], x2);
      }
#pragma unroll
      for (int off = 1; off < 16; off <<= 1) {
        x1 += __shfl_xor(x1, off);
        x2 += __shfl_xor(x2, off);
      }
      p1[rt][q] = x1; p2[rt][q] = x2;
    }
  __syncthreads();
  if (lr == 0) {
#pragma unroll
    for (int rt = 0; rt < 2; ++rt)
#pragma unroll
      for (int q = 0; q < 4; ++q) {
        sred[w][0][rt * 16 + lg * 4 + q] = p1[rt][q];
        sred[w][1][rt * 16 + lg * 4 + q] = p2[rt][q];
      }
  }
  __syncthreads();
  if (t < 32) {
    float v1s = 0.f, v2s = 0.f;
#pragma unroll
    for (int ww = 0; ww < 8; ++ww) { v1s += sred[ww][0][t]; v2s += sred[ww][1][t]; }
    const int r = rb + t;
    s1[r] = v1s;
    e2[r] = __expf(v2s);
    e02[r] = __expf(SLOPE * v2s);
  }
}

// ---------------- K3: per-row Z -> rowinfo {E1*iz, E01*iz, T, iz} ----------------
__global__ __launch_bounds__(256) void k_z(
    const float* __restrict__ s1, const float* __restrict__ e2g,
    const float* __restrict__ e02g, const float* __restrict__ abp,
    float* __restrict__ rowinfo)
{
  __shared__ __align__(16) float es[8192];
  __shared__ __align__(16) float fs[8192];
  const int t = threadIdx.x;
  for (int i = t * 4; i < 8192; i += 1024) {
    *reinterpret_cast<f32x4*>(&es[i]) = *reinterpret_cast<const f32x4*>(e2g + i);
    *reinterpret_cast<f32x4*>(&fs[i]) = *reinterpret_cast<const f32x4*>(e02g + i);
  }
  __syncthreads();
  const int w = t >> 6, l = t & 63;
  const float ab = abp[0];
  const int rb = blockIdx.x * 16 + w * 4;
  float T[4], E1[4], E01[4];
#pragma unroll
  for (int rr = 0; rr < 4; ++rr) {
    const float s1a = s1[rb + rr] + ab;
    E1[rr] = __expf(s1a); E01[rr] = __expf(SLOPE * s1a); T[rr] = __expf(-s1a);
  }
  float zA[4] = {0.f,0.f,0.f,0.f}, zB[4] = {0.f,0.f,0.f,0.f};
  for (int i = l * 4; i < 8192; i += 256) {
    const f32x4 e = *reinterpret_cast<const f32x4*>(&es[i]);
    const f32x4 f = *reinterpret_cast<const f32x4*>(&fs[i]);
#pragma unroll
    for (int rr = 0; rr < 4; ++rr)
#pragma unroll
      for (int q = 0; q < 4; ++q) {
        const bool c = (e[q] >= T[rr]);
        zA[rr] += c ? e[q] : 0.f;
        zB[rr] += c ? 0.f : f[q];
      }
  }
#pragma unroll
  for (int rr = 0; rr < 4; ++rr) {
    float z = E1[rr] * zA[rr] + E01[rr] * zB[rr];
#pragma unroll
    for (int off = 32; off > 0; off >>= 1) z += __shfl_down(z, off);
    if (l == 0) {
      const float iz = 1.0f / z;
      f32x4 ri = (f32x4){E1[rr] * iz, E01[rr] * iz, T[rr], iz};
      *reinterpret_cast<f32x4*>(rowinfo + (size_t)(rb + rr) * 4) = ri;
    }
  }
}

// ---------------- K4: att + partial out — r9 structure, REP=4 diagnostic ----------------
__global__ __launch_bounds__(512, 4) void k_att(
    const float* __restrict__ rowinfo, const float* __restrict__ e2g,
    const float* __restrict__ e02g, const unsigned short* __restrict__ ht,
    float* __restrict__ att, float* __restrict__ part, int CHUNK)
{
  extern __shared__ __align__(16) char smem[];
  char* plsb  = smem;                                    // [2][4][64] short8 = 8 KB
  float* e2s  = reinterpret_cast<float*>(smem + 8192);   // CHUNK
  float* e02s = e2s + CHUNK;                             // CHUNK

  const int t = threadIdx.x, w = t >> 6, l = t & 63;
  const int lr = l & 15, lg = l >> 4;
  const int kbase = blockIdx.x * CHUNK;     // slice (fastest -> XCD)
  const int rb = blockIdx.y * 64;

  for (int i = t * 4; i < CHUNK; i += 2048) {
    *reinterpret_cast<f32x4*>(e2s + i)  = *reinterpret_cast<const f32x4*>(e2g + kbase + i);
    *reinterpret_cast<f32x4*>(e02s + i) = *reinterpret_cast<const f32x4*>(e02g + kbase + i);
  }

  const int r = l >> 3, jc = l & 7;
  const int rowW = rb + w * 8 + r;
  const f32x4 ri = *reinterpret_cast<const f32x4*>(rowinfo + (size_t)rowW * 4);
  const float E1z = ri[0], E01z = ri[1], T = ri[2];
  float* attW = att + (size_t)rowW * 8192 + kbase + jc * 4;
  const int fragoff = (w >> 1) * 1024 + ((jc >> 1) * 16 + (w & 1) * 8 + r) * 16 + (jc & 1) * 8;

  __syncthreads();

  auto gen = [&](int kw, int pb) {
    const f32x4 eA = *reinterpret_cast<const f32x4*>(e2s + kw + jc * 4);
    const f32x4 fA = *reinterpret_cast<const f32x4*>(e02s + kw + jc * 4);
    f32x4 pA;
#pragma unroll
    for (int q = 0; q < 4; ++q) {
      const bool cA = (eA[q] >= T);
      pA[q] = (cA ? E1z : E01z) * (cA ? eA[q] : fA[q]);
    }
    __builtin_nontemporal_store(pA, reinterpret_cast<f32x4*>(attW + kw));
    uint2 u;
    u.x = cvt_pk_bf16(pA[0], pA[1]); u.y = cvt_pk_bf16(pA[2], pA[3]);
    *reinterpret_cast<uint2*>(plsb + pb * 4096 + fragoff) = u;
  };

  const unsigned short* hbase = ht + (size_t)(w * 32 + lr) * 8192 + kbase + lg * 8;
  auto loadB = [&](short8* b, int n) {
    const int kk = n * 32;
    b[0] = *reinterpret_cast<const short8*>(hbase + kk);
    b[1] = *reinterpret_cast<const short8*>(hbase + kk + (size_t)16 * 8192);
  };

  f32x4 acc[4][2];

  auto mma = [&](const short8* b, const short8& af0, const short8& af1,
                 const short8& af2, const short8& af3) {
    __builtin_amdgcn_s_setprio(1);
    acc[0][0] = __builtin_amdgcn_mfma_f32_16x16x32_bf16(af0, b[0], acc[0][0], 0, 0, 0);
    acc[1][0] = __builtin_amdgcn_mfma_f32_16x16x32_bf16(af1, b[0], acc[1][0], 0, 0, 0);
    acc[2][0] = __builtin_amdgcn_mfma_f32_16x16x32_bf16(af2, b[0], acc[2][0], 0, 0, 0);
    acc[3][0] = __builtin_amdgcn_mfma_f32_16x16x32_bf16(af3, b[0], acc[3][0], 0, 0, 0);
    acc[0][1] = __builtin_amdgcn_mfma_f32_16x16x32_bf16(af0, b[1], acc[0][1], 0, 0, 0);
    acc[1][1] = __builtin_amdgcn_mfma_f32_16x16x32_bf16(af1, b[1], acc[1][1], 0, 0, 0);
    acc[2][1] = __builtin_amdgcn_mfma_f32_16x16x32_bf16(af2, b[1], acc[2][1], 0, 0, 0);
    acc[3][1] = __builtin_amdgcn_mfma_f32_16x16x32_bf16(af3, b[1], acc[3][1], 0, 0, 0);
    __builtin_amdgcn_s_setprio(0);
  };

  const int NIT = CHUNK / 32;   // even
  const short8* buf0 = reinterpret_cast<const short8*>(plsb);
  const short8* buf1 = reinterpret_cast<const short8*>(plsb + 4096);
  short8 bAr[2], bBr[2];

  // DIAGNOSTIC: repeat the full pipeline 4x (idempotent att rewrite; acc
  // re-zeroed per rep; part written once). Makes this dispatch ~4x longer so
  // it surfaces in rocprof top-5 with full counters.
  for (int rep = 0; rep < 4; ++rep) {
#pragma unroll
    for (int rt = 0; rt < 4; ++rt)
#pragma unroll
      for (int ct = 0; ct < 2; ++ct) acc[rt][ct] = (f32x4){0.f, 0.f, 0.f, 0.f};

    loadB(bAr, 0);
    gen(0, 0);

    for (int n = 0; n < NIT; n += 2) {
      if (n + 1 < NIT) loadB(bBr, n + 1);
      asm volatile("s_waitcnt lgkmcnt(0)\n\ts_barrier" ::: "memory");
      {
        const short8 af0 = buf0[0 * 64 + l];
        const short8 af1 = buf0[1 * 64 + l];
        const short8 af2 = buf0[2 * 64 + l];
        const short8 af3 = buf0[3 * 64 + l];
        if (n + 1 < NIT) gen((n + 1) * 32, 1);
        mma(bAr, af0, af1, af2, af3);
      }
      if (n + 1 >= NIT) break;
      if (n + 2 < NIT) loadB(bAr, n + 2);
      asm volatile("s_waitcnt lgkmcnt(0)\n\ts_barrier" ::: "memory");
      {
        const short8 af0 = buf1[0 * 64 + l];
        const short8 af1 = buf1[1 * 64 + l];
        const short8 af2 = buf1[2 * 64 + l];
        const short8 af3 = buf1[3 * 64 + l];
        if (n + 2 < NIT) gen((n + 2) * 32, 0);
        mma(bBr, af0, af1, af2, af3);
      }
    }
  }

  float* pb = part + (size_t)blockIdx.x * ((size_t)NROW * DDIM);
#pragma unroll
  for (int rt = 0; rt < 4; ++rt)
#pragma unroll
    for (int ct = 0; ct < 2; ++ct)
#pragma unroll
      for (int q = 0; q < 4; ++q)
        __builtin_nontemporal_store(acc[rt][ct][q],
            pb + (size_t)(rb + rt * 16 + lg * 4 + q) * 256 + w * 32 + ct * 16 + lr);
}

// ---------------- K5: out = lrelu(sum_k part[k]) ----------------
__global__ __launch_bounds__(256) void k_reduce(
    const float* __restrict__ part, float* __restrict__ out, int KS)
{
  const size_t idx = ((size_t)blockIdx.x * 256 + threadIdx.x) * 4;
  f32x4 s = __builtin_nontemporal_load(reinterpret_cast<const f32x4*>(part + idx));
  for (int k = 1; k < KS; ++k) {
    const f32x4 v = __builtin_nontemporal_load(
        reinterpret_cast<const f32x4*>(part + (size_t)k * NROW * DDIM + idx));
#pragma unroll
    for (int q = 0; q < 4; ++q) s[q] += v[q];
  }
#pragma unroll
  for (int q = 0; q < 4; ++q) s[q] = lrelu(s[q]);
  __builtin_nontemporal_store(s, reinterpret_cast<f32x4*>(out + idx));
}

extern "C" void kernel_launch(void* const* d_in, const int* in_sizes, int n_in,
                              void* d_out, int out_size, void* d_ws, size_t ws_size,
                              hipStream_t stream)
{
  const float* doc = (const float*)d_in[0];
  const float* W   = (const float*)d_in[1];
  const float* Wb  = (const float*)d_in[2];
  const float* a   = (const float*)d_in[3];
  const float* ab  = (const float*)d_in[4];

  float* out = (float*)d_out;                 // 8192*256
  float* att = out + (size_t)8192 * 256;      // 8192*8192

  char* ws = (char*)d_ws;
  unsigned short* ht    = (unsigned short*)ws;                              // 4 MB
  unsigned short* Wt_hi = (unsigned short*)(ws + (size_t)4 * 1024 * 1024);  // 256 KB
  unsigned short* Wt_lo = Wt_hi + (size_t)256 * 512;                        // 256 KB
  float* s1      = (float*)(ws + (size_t)4 * 1024 * 1024 + 512 * 1024);     // 32 KB
  float* e2      = s1 + 8192;
  float* e02     = e2 + 8192;
  float* rowinfo = e02 + 8192;                                              // 128 KB
  const size_t base = (size_t)5 * 1024 * 1024;
  const size_t partBytes = (size_t)NROW * DDIM * sizeof(float);             // 8 MB

  int KS = 1;
  for (int c = 4; c >= 1; c >>= 1)
    if (base + (size_t)c * partBytes <= ws_size) { KS = c; break; }
  float* part = (float*)(ws + base);
  const int CHUNK = NROW / KS;
  const size_t smem = 8192 + (size_t)2 * CHUNK * sizeof(float);

  hipLaunchKernelGGL(k_prep,   dim3(128),     dim3(256), 0,    stream, W, Wt_hi, Wt_lo);
  hipLaunchKernelGGL(k_h,      dim3(256),     dim3(512), 0,    stream, doc, Wt_hi, Wt_lo, Wb, a, ht, s1, e2, e02);
  hipLaunchKernelGGL(k_z,      dim3(512),     dim3(256), 0,    stream, s1, e2, e02, ab, rowinfo);
  hipLaunchKernelGGL(k_att,    dim3(KS, 128), dim3(512), smem, stream, rowinfo, e2, e02, ht, att, part, CHUNK);
  hipLaunchKernelGGL(k_reduce, dim3(2048),    dim3(256), 0,    stream, part, out, KS);
}

// Round 15
// 133.356 us; speedup vs baseline: 2.3786x; 2.3786x over previous
//
#include <hip/hip_runtime.h>
#include <hip/hip_bf16.h>

// GAT layer — r9 structure (best: 130.4 us), single change vs r9:
// att stores are PLAIN (through L2 write-aggregation) instead of nontemporal.
// r14 diagnostic: k_att = 69 us/rep, 4.0 TB/s (50% peak), no amplification,
// VALU 14% / MFMA 5% -> store-throughput-bound. Fill kernel (plain writes)
// sustains 6.8 TB/s on this chip; this tests nt vs plain at SAME occupancy.

typedef __attribute__((ext_vector_type(4))) float f32x4;
typedef __attribute__((ext_vector_type(8))) short short8;
typedef __attribute__((ext_vector_type(4))) unsigned short ushort4v;

#define SLOPE 0.1f
#define NROW 8192
#define DDIM 256

__device__ __forceinline__ float lrelu(float x){ return fmaxf(x, SLOPE * x); }

__device__ __forceinline__ unsigned short f2bf(float f){
  union { float f; unsigned u; } v; v.f = f;
  unsigned r = (v.u + 0x7fffu + ((v.u >> 16) & 1u)) >> 16;
  return (unsigned short)r;
}
__device__ __forceinline__ float bf2f(unsigned short u){
  union { unsigned u; float f; } v; v.u = (unsigned)u << 16; return v.f;
}
__device__ __forceinline__ unsigned cvt_pk_bf16(float lo, float hi){
  unsigned r;
  asm("v_cvt_pk_bf16_f32 %0, %1, %2" : "=v"(r) : "v"(lo), "v"(hi));
  return r;
}

// ---------------- K0: Wt_hi/Wt_lo [256][512] bf16 split-transpose of W ----------------
__global__ __launch_bounds__(256) void k_prep(
    const float* __restrict__ W,
    unsigned short* __restrict__ Wt_hi, unsigned short* __restrict__ Wt_lo)
{
  const int tid = blockIdx.x * 256 + threadIdx.x;   // 32768 total
  const int c = tid >> 7, kq = tid & 127;
  ushort4v hi, lo;
#pragma unroll
  for (int j = 0; j < 4; ++j) {
    const float v = W[(size_t)(kq * 4 + j) * 256 + c];
    hi[j] = f2bf(v);
    lo[j] = f2bf(v - bf2f(hi[j]));
  }
  *reinterpret_cast<ushort4v*>(Wt_hi + (size_t)c * 512 + kq * 4) = hi;
  *reinterpret_cast<ushort4v*>(Wt_lo + (size_t)c * 512 + kq * 4) = lo;
}

// ---------------- K1: h-tile via split MFMA; fused s1/s2/e2/e02 + ht bf16 ----------------
__global__ __launch_bounds__(512, 2) void k_h(
    const float* __restrict__ doc, const unsigned short* __restrict__ Wt_hi,
    const unsigned short* __restrict__ Wt_lo, const float* __restrict__ Wb,
    const float* __restrict__ a,
    unsigned short* __restrict__ ht, float* __restrict__ s1,
    float* __restrict__ e2, float* __restrict__ e02)
{
  __shared__ __align__(16) short8 aH[2][2][64];
  __shared__ __align__(16) short8 aL[2][2][64];
  __shared__ float sred[8][2][32];

  const int t = threadIdx.x, w = t >> 6, l = t & 63;
  const int lr = l & 15, lg = l >> 4;
  const int rb = blockIdx.x * 32;
  const int cb = w * 32;

  f32x4 acc[2][2];
#pragma unroll
  for (int rt = 0; rt < 2; ++rt)
#pragma unroll
    for (int ct = 0; ct < 2; ++ct) acc[rt][ct] = (f32x4){0.f, 0.f, 0.f, 0.f};

  const float* docp = doc + (size_t)(rb + w * 16 + lr) * 512 + lg * 8;  // valid for w<2

  f32x4 v0, v1;
  auto loadDoc = [&](int k0) { if (w < 2) {
      v0 = *reinterpret_cast<const f32x4*>(docp + k0);
      v1 = *reinterpret_cast<const f32x4*>(docp + k0 + 4);
  }};
  auto writeStage = [&](int pb) { if (w < 2) {
      union { short8 v; unsigned short u[8]; } hi, lo;
#pragma unroll
      for (int q = 0; q < 4; ++q) {
        hi.u[q] = f2bf(v0[q]);     lo.u[q] = f2bf(v0[q] - bf2f(hi.u[q]));
        hi.u[4+q] = f2bf(v1[q]);   lo.u[4+q] = f2bf(v1[q] - bf2f(hi.u[4+q]));
      }
      aH[pb][w][l] = hi.v;
      aL[pb][w][l] = lo.v;
  }};

  loadDoc(0); writeStage(0); loadDoc(32);

  for (int n = 0; n < 16; ++n) {
    const int kk = n * 32;
    const int par = n & 1;

    asm volatile("s_waitcnt lgkmcnt(0)\n\ts_barrier" ::: "memory");

    const short8 ah0 = aH[par][0][l];
    const short8 ah1 = aH[par][1][l];
    const short8 al0 = aL[par][0][l];
    const short8 al1 = aL[par][1][l];

    short8 bh[2], bl[2];
#pragma unroll
    for (int ct = 0; ct < 2; ++ct) {
      const size_t off = (size_t)(cb + ct * 16 + lr) * 512 + kk + lg * 8;
      bh[ct] = *reinterpret_cast<const short8*>(Wt_hi + off);
      bl[ct] = *reinterpret_cast<const short8*>(Wt_lo + off);
    }

    if (n + 1 < 16) writeStage(par ^ 1);
    if (n + 2 < 16) loadDoc((n + 2) * 32);

#pragma unroll
    for (int ct = 0; ct < 2; ++ct) {
      acc[0][ct] = __builtin_amdgcn_mfma_f32_16x16x32_bf16(ah0, bh[ct], acc[0][ct], 0, 0, 0);
      acc[1][ct] = __builtin_amdgcn_mfma_f32_16x16x32_bf16(ah1, bh[ct], acc[1][ct], 0, 0, 0);
      acc[0][ct] = __builtin_amdgcn_mfma_f32_16x16x32_bf16(ah0, bl[ct], acc[0][ct], 0, 0, 0);
      acc[1][ct] = __builtin_amdgcn_mfma_f32_16x16x32_bf16(ah1, bl[ct], acc[1][ct], 0, 0, 0);
      acc[0][ct] = __builtin_amdgcn_mfma_f32_16x16x32_bf16(al0, bh[ct], acc[0][ct], 0, 0, 0);
      acc[1][ct] = __builtin_amdgcn_mfma_f32_16x16x32_bf16(al1, bh[ct], acc[1][ct], 0, 0, 0);
    }
  }

  float bias[2];
#pragma unroll
  for (int ct = 0; ct < 2; ++ct) bias[ct] = Wb[cb + ct * 16 + lr];
#pragma unroll
  for (int rt = 0; rt < 2; ++rt)
#pragma unroll
    for (int ct = 0; ct < 2; ++ct) {
#pragma unroll
      for (int q = 0; q < 4; ++q) acc[rt][ct][q] += bias[ct];
      ushort4v u;
#pragma unroll
      for (int q = 0; q < 4; ++q) u[q] = f2bf(acc[rt][ct][q]);
      *reinterpret_cast<ushort4v*>(
          ht + (size_t)(cb + ct * 16 + lr) * 8192 + rb + rt * 16 + lg * 4) = u;
    }

  float a1c[2], a2c[2];
#pragma unroll
  for (int ct = 0; ct < 2; ++ct) {
    a1c[ct] = a[cb + ct * 16 + lr];
    a2c[ct] = a[256 + cb + ct * 16 + lr];
  }
  float p1[2][4], p2[2][4];
#pragma unroll
  for (int rt = 0; rt < 2; ++rt)
#pragma unroll
    for (int q = 0; q < 4; ++q) {
      float x1 = 0.f, x2 = 0.f;
#pragma unroll
      for (int ct = 0; ct < 2; ++ct) {
        x1 = fmaf(acc[rt][ct][q], a1c[ct], x1);
        x2 = fmaf(acc[rt][ct][q], a2c[ct], x2);
      }
#pragma unroll
      for (int off = 1; off < 16; off <<= 1) {
        x1 += __shfl_xor(x1, off);
        x2 += __shfl_xor(x2, off);
      }
      p1[rt][q] = x1; p2[rt][q] = x2;
    }
  __syncthreads();
  if (lr == 0) {
#pragma unroll
    for (int rt = 0; rt < 2; ++rt)
#pragma unroll
      for (int q = 0; q < 4; ++q) {
        sred[w][0][rt * 16 + lg * 4 + q] = p1[rt][q];
        sred[w][1][rt * 16 + lg * 4 + q] = p2[rt][q];
      }
  }
  __syncthreads();
  if (t < 32) {
    float v1s = 0.f, v2s = 0.f;
#pragma unroll
    for (int ww = 0; ww < 8; ++ww) { v1s += sred[ww][0][t]; v2s += sred[ww][1][t]; }
    const int r = rb + t;
    s1[r] = v1s;
    e2[r] = __expf(v2s);
    e02[r] = __expf(SLOPE * v2s);
  }
}

// ---------------- K3: per-row Z -> rowinfo {E1*iz, E01*iz, T, iz} ----------------
__global__ __launch_bounds__(256) void k_z(
    const float* __restrict__ s1, const float* __restrict__ e2g,
    const float* __restrict__ e02g, const float* __restrict__ abp,
    float* __restrict__ rowinfo)
{
  __shared__ __align__(16) float es[8192];
  __shared__ __align__(16) float fs[8192];
  const int t = threadIdx.x;
  for (int i = t * 4; i < 8192; i += 1024) {
    *reinterpret_cast<f32x4*>(&es[i]) = *reinterpret_cast<const f32x4*>(e2g + i);
    *reinterpret_cast<f32x4*>(&fs[i]) = *reinterpret_cast<const f32x4*>(e02g + i);
  }
  __syncthreads();
  const int w = t >> 6, l = t & 63;
  const float ab = abp[0];
  const int rb = blockIdx.x * 16 + w * 4;
  float T[4], E1[4], E01[4];
#pragma unroll
  for (int rr = 0; rr < 4; ++rr) {
    const float s1a = s1[rb + rr] + ab;
    E1[rr] = __expf(s1a); E01[rr] = __expf(SLOPE * s1a); T[rr] = __expf(-s1a);
  }
  float zA[4] = {0.f,0.f,0.f,0.f}, zB[4] = {0.f,0.f,0.f,0.f};
  for (int i = l * 4; i < 8192; i += 256) {
    const f32x4 e = *reinterpret_cast<const f32x4*>(&es[i]);
    const f32x4 f = *reinterpret_cast<const f32x4*>(&fs[i]);
#pragma unroll
    for (int rr = 0; rr < 4; ++rr)
#pragma unroll
      for (int q = 0; q < 4; ++q) {
        const bool c = (e[q] >= T[rr]);
        zA[rr] += c ? e[q] : 0.f;
        zB[rr] += c ? 0.f : f[q];
      }
  }
#pragma unroll
  for (int rr = 0; rr < 4; ++rr) {
    float z = E1[rr] * zA[rr] + E01[rr] * zB[rr];
#pragma unroll
    for (int off = 32; off > 0; off >>= 1) z += __shfl_down(z, off);
    if (l == 0) {
      const float iz = 1.0f / z;
      f32x4 ri = (f32x4){E1[rr] * iz, E01[rr] * iz, T[rr], iz};
      *reinterpret_cast<f32x4*>(rowinfo + (size_t)(rb + rr) * 4) = ri;
    }
  }
}

// ---------------- K4: att + partial out via MFMA (r9 structure, plain att stores) ----------------
__global__ __launch_bounds__(512, 4) void k_att(
    const float* __restrict__ rowinfo, const float* __restrict__ e2g,
    const float* __restrict__ e02g, const unsigned short* __restrict__ ht,
    float* __restrict__ att, float* __restrict__ part, int CHUNK)
{
  extern __shared__ __align__(16) char smem[];
  char* plsb  = smem;                                    // [2][4][64] short8 = 8 KB
  float* e2s  = reinterpret_cast<float*>(smem + 8192);   // CHUNK
  float* e02s = e2s + CHUNK;                             // CHUNK

  const int t = threadIdx.x, w = t >> 6, l = t & 63;
  const int lr = l & 15, lg = l >> 4;
  const int kbase = blockIdx.x * CHUNK;     // slice (fastest -> XCD)
  const int rb = blockIdx.y * 64;

  for (int i = t * 4; i < CHUNK; i += 2048) {
    *reinterpret_cast<f32x4*>(e2s + i)  = *reinterpret_cast<const f32x4*>(e2g + kbase + i);
    *reinterpret_cast<f32x4*>(e02s + i) = *reinterpret_cast<const f32x4*>(e02g + kbase + i);
  }

  const int r = l >> 3, jc = l & 7;
  const int rowW = rb + w * 8 + r;
  const f32x4 ri = *reinterpret_cast<const f32x4*>(rowinfo + (size_t)rowW * 4);
  const float E1z = ri[0], E01z = ri[1], T = ri[2];
  float* attW = att + (size_t)rowW * 8192 + kbase + jc * 4;
  const int fragoff = (w >> 1) * 1024 + ((jc >> 1) * 16 + (w & 1) * 8 + r) * 16 + (jc & 1) * 8;

  __syncthreads();

  auto gen = [&](int kw, int pb) {
    const f32x4 eA = *reinterpret_cast<const f32x4*>(e2s + kw + jc * 4);
    const f32x4 fA = *reinterpret_cast<const f32x4*>(e02s + kw + jc * 4);
    f32x4 pA;
#pragma unroll
    for (int q = 0; q < 4; ++q) {
      const bool cA = (eA[q] >= T);
      pA[q] = (cA ? E1z : E01z) * (cA ? eA[q] : fA[q]);
    }
    *reinterpret_cast<f32x4*>(attW + kw) = pA;   // PLAIN store (single change vs r9)
    uint2 u;
    u.x = cvt_pk_bf16(pA[0], pA[1]); u.y = cvt_pk_bf16(pA[2], pA[3]);
    *reinterpret_cast<uint2*>(plsb + pb * 4096 + fragoff) = u;
  };

  const unsigned short* hbase = ht + (size_t)(w * 32 + lr) * 8192 + kbase + lg * 8;
  auto loadB = [&](short8* b, int n) {
    const int kk = n * 32;
    b[0] = *reinterpret_cast<const short8*>(hbase + kk);
    b[1] = *reinterpret_cast<const short8*>(hbase + kk + (size_t)16 * 8192);
  };

  f32x4 acc[4][2];
#pragma unroll
  for (int rt = 0; rt < 4; ++rt)
#pragma unroll
    for (int ct = 0; ct < 2; ++ct) acc[rt][ct] = (f32x4){0.f, 0.f, 0.f, 0.f};

  auto mma = [&](const short8* b, const short8& af0, const short8& af1,
                 const short8& af2, const short8& af3) {
    __builtin_amdgcn_s_setprio(1);
    acc[0][0] = __builtin_amdgcn_mfma_f32_16x16x32_bf16(af0, b[0], acc[0][0], 0, 0, 0);
    acc[1][0] = __builtin_amdgcn_mfma_f32_16x16x32_bf16(af1, b[0], acc[1][0], 0, 0, 0);
    acc[2][0] = __builtin_amdgcn_mfma_f32_16x16x32_bf16(af2, b[0], acc[2][0], 0, 0, 0);
    acc[3][0] = __builtin_amdgcn_mfma_f32_16x16x32_bf16(af3, b[0], acc[3][0], 0, 0, 0);
    acc[0][1] = __builtin_amdgcn_mfma_f32_16x16x32_bf16(af0, b[1], acc[0][1], 0, 0, 0);
    acc[1][1] = __builtin_amdgcn_mfma_f32_16x16x32_bf16(af1, b[1], acc[1][1], 0, 0, 0);
    acc[2][1] = __builtin_amdgcn_mfma_f32_16x16x32_bf16(af2, b[1], acc[2][1], 0, 0, 0);
    acc[3][1] = __builtin_amdgcn_mfma_f32_16x16x32_bf16(af3, b[1], acc[3][1], 0, 0, 0);
    __builtin_amdgcn_s_setprio(0);
  };

  short8 bAr[2], bBr[2];
  loadB(bAr, 0);          // b(0) issued before gen(0)'s store
  gen(0, 0);

  const int NIT = CHUNK / 32;   // even
  const short8* buf0 = reinterpret_cast<const short8*>(plsb);
  const short8* buf1 = reinterpret_cast<const short8*>(plsb + 4096);

  for (int n = 0; n < NIT; n += 2) {
    if (n + 1 < NIT) loadB(bBr, n + 1);
    asm volatile("s_waitcnt lgkmcnt(0)\n\ts_barrier" ::: "memory");
    {
      const short8 af0 = buf0[0 * 64 + l];
      const short8 af1 = buf0[1 * 64 + l];
      const short8 af2 = buf0[2 * 64 + l];
      const short8 af3 = buf0[3 * 64 + l];
      if (n + 1 < NIT) gen((n + 1) * 32, 1);
      mma(bAr, af0, af1, af2, af3);
    }
    if (n + 1 >= NIT) break;
    if (n + 2 < NIT) loadB(bAr, n + 2);
    asm volatile("s_waitcnt lgkmcnt(0)\n\ts_barrier" ::: "memory");
    {
      const short8 af0 = buf1[0 * 64 + l];
      const short8 af1 = buf1[1 * 64 + l];
      const short8 af2 = buf1[2 * 64 + l];
      const short8 af3 = buf1[3 * 64 + l];
      if (n + 2 < NIT) gen((n + 2) * 32, 0);
      mma(bBr, af0, af1, af2, af3);
    }
  }

  float* pb = part + (size_t)blockIdx.x * ((size_t)NROW * DDIM);
#pragma unroll
  for (int rt = 0; rt < 4; ++rt)
#pragma unroll
    for (int ct = 0; ct < 2; ++ct)
#pragma unroll
      for (int q = 0; q < 4; ++q)
        __builtin_nontemporal_store(acc[rt][ct][q],
            pb + (size_t)(rb + rt * 16 + lg * 4 + q) * 256 + w * 32 + ct * 16 + lr);
}

// ---------------- K5: out = lrelu(sum_k part[k]) ----------------
__global__ __launch_bounds__(256) void k_reduce(
    const float* __restrict__ part, float* __restrict__ out, int KS)
{
  const size_t idx = ((size_t)blockIdx.x * 256 + threadIdx.x) * 4;
  f32x4 s = __builtin_nontemporal_load(reinterpret_cast<const f32x4*>(part + idx));
  for (int k = 1; k < KS; ++k) {
    const f32x4 v = __builtin_nontemporal_load(
        reinterpret_cast<const f32x4*>(part + (size_t)k * NROW * DDIM + idx));
#pragma unroll
    for (int q = 0; q < 4; ++q) s[q] += v[q];
  }
#pragma unroll
  for (int q = 0; q < 4; ++q) s[q] = lrelu(s[q]);
  __builtin_nontemporal_store(s, reinterpret_cast<f32x4*>(out + idx));
}

extern "C" void kernel_launch(void* const* d_in, const int* in_sizes, int n_in,
                              void* d_out, int out_size, void* d_ws, size_t ws_size,
                              hipStream_t stream)
{
  const float* doc = (const float*)d_in[0];
  const float* W   = (const float*)d_in[1];
  const float* Wb  = (const float*)d_in[2];
  const float* a   = (const float*)d_in[3];
  const float* ab  = (const float*)d_in[4];

  float* out = (float*)d_out;                 // 8192*256
  float* att = out + (size_t)8192 * 256;      // 8192*8192

  char* ws = (char*)d_ws;
  unsigned short* ht    = (unsigned short*)ws;                              // 4 MB
  unsigned short* Wt_hi = (unsigned short*)(ws + (size_t)4 * 1024 * 1024);  // 256 KB
  unsigned short* Wt_lo = Wt_hi + (size_t)256 * 512;                        // 256 KB
  float* s1      = (float*)(ws + (size_t)4 * 1024 * 1024 + 512 * 1024);     // 32 KB
  float* e2      = s1 + 8192;
  float* e02     = e2 + 8192;
  float* rowinfo = e02 + 8192;                                              // 128 KB
  const size_t base = (size_t)5 * 1024 * 1024;
  const size_t partBytes = (size_t)NROW * DDIM * sizeof(float);             // 8 MB

  int KS = 1;
  for (int c = 4; c >= 1; c >>= 1)
    if (base + (size_t)c * partBytes <= ws_size) { KS = c; break; }
  float* part = (float*)(ws + base);
  const int CHUNK = NROW / KS;
  const size_t smem = 8192 + (size_t)2 * CHUNK * sizeof(float);

  hipLaunchKernelGGL(k_prep,   dim3(128),     dim3(256), 0,    stream, W, Wt_hi, Wt_lo);
  hipLaunchKernelGGL(k_h,      dim3(256),     dim3(512), 0,    stream, doc, Wt_hi, Wt_lo, Wb, a, ht, s1, e2, e02);
  hipLaunchKernelGGL(k_z,      dim3(512),     dim3(256), 0,    stream, s1, e2, e02, ab, rowinfo);
  hipLaunchKernelGGL(k_att,    dim3(KS, 128), dim3(512), smem, stream, rowinfo, e2, e02, ht, att, part, CHUNK);
  hipLaunchKernelGGL(k_reduce, dim3(2048),    dim3(256), 0,    stream, part, out, KS);
}

// Round 16
// 128.188 us; speedup vs baseline: 2.4745x; 1.0403x over previous
//
#include <hip/hip_runtime.h>
#include <hip/hip_bf16.h>

// GAT layer — r9 structure (best: 130.4 us), single change vs r9:
// k_att gen2 produces TWO consecutive 32-k windows per call, so each att row
// receives 256 B CONTIGUOUS per visit (2 back-to-back nt stores) instead of
// 128 B. Tests the DRAM-burst-granularity theory for the 4.0 TB/s write cap
// (r14 counters: no amplification, VALU 14%, MFMA 5%, 81% stall).

typedef __attribute__((ext_vector_type(4))) float f32x4;
typedef __attribute__((ext_vector_type(8))) short short8;
typedef __attribute__((ext_vector_type(4))) unsigned short ushort4v;

#define SLOPE 0.1f
#define NROW 8192
#define DDIM 256

__device__ __forceinline__ float lrelu(float x){ return fmaxf(x, SLOPE * x); }

__device__ __forceinline__ unsigned short f2bf(float f){
  union { float f; unsigned u; } v; v.f = f;
  unsigned r = (v.u + 0x7fffu + ((v.u >> 16) & 1u)) >> 16;
  return (unsigned short)r;
}
__device__ __forceinline__ float bf2f(unsigned short u){
  union { unsigned u; float f; } v; v.u = (unsigned)u << 16; return v.f;
}
__device__ __forceinline__ unsigned cvt_pk_bf16(float lo, float hi){
  unsigned r;
  asm("v_cvt_pk_bf16_f32 %0, %1, %2" : "=v"(r) : "v"(lo), "v"(hi));
  return r;
}

// ---------------- K0: Wt_hi/Wt_lo [256][512] bf16 split-transpose of W ----------------
__global__ __launch_bounds__(256) void k_prep(
    const float* __restrict__ W,
    unsigned short* __restrict__ Wt_hi, unsigned short* __restrict__ Wt_lo)
{
  const int tid = blockIdx.x * 256 + threadIdx.x;   // 32768 total
  const int c = tid >> 7, kq = tid & 127;
  ushort4v hi, lo;
#pragma unroll
  for (int j = 0; j < 4; ++j) {
    const float v = W[(size_t)(kq * 4 + j) * 256 + c];
    hi[j] = f2bf(v);
    lo[j] = f2bf(v - bf2f(hi[j]));
  }
  *reinterpret_cast<ushort4v*>(Wt_hi + (size_t)c * 512 + kq * 4) = hi;
  *reinterpret_cast<ushort4v*>(Wt_lo + (size_t)c * 512 + kq * 4) = lo;
}

// ---------------- K1: h-tile via split MFMA; fused s1/s2/e2/e02 + ht bf16 ----------------
__global__ __launch_bounds__(512, 2) void k_h(
    const float* __restrict__ doc, const unsigned short* __restrict__ Wt_hi,
    const unsigned short* __restrict__ Wt_lo, const float* __restrict__ Wb,
    const float* __restrict__ a,
    unsigned short* __restrict__ ht, float* __restrict__ s1,
    float* __restrict__ e2, float* __restrict__ e02)
{
  __shared__ __align__(16) short8 aH[2][2][64];
  __shared__ __align__(16) short8 aL[2][2][64];
  __shared__ float sred[8][2][32];

  const int t = threadIdx.x, w = t >> 6, l = t & 63;
  const int lr = l & 15, lg = l >> 4;
  const int rb = blockIdx.x * 32;
  const int cb = w * 32;

  f32x4 acc[2][2];
#pragma unroll
  for (int rt = 0; rt < 2; ++rt)
#pragma unroll
    for (int ct = 0; ct < 2; ++ct) acc[rt][ct] = (f32x4){0.f, 0.f, 0.f, 0.f};

  const float* docp = doc + (size_t)(rb + w * 16 + lr) * 512 + lg * 8;  // valid for w<2

  f32x4 v0, v1;
  auto loadDoc = [&](int k0) { if (w < 2) {
      v0 = *reinterpret_cast<const f32x4*>(docp + k0);
      v1 = *reinterpret_cast<const f32x4*>(docp + k0 + 4);
  }};
  auto writeStage = [&](int pb) { if (w < 2) {
      union { short8 v; unsigned short u[8]; } hi, lo;
#pragma unroll
      for (int q = 0; q < 4; ++q) {
        hi.u[q] = f2bf(v0[q]);     lo.u[q] = f2bf(v0[q] - bf2f(hi.u[q]));
        hi.u[4+q] = f2bf(v1[q]);   lo.u[4+q] = f2bf(v1[q] - bf2f(hi.u[4+q]));
      }
      aH[pb][w][l] = hi.v;
      aL[pb][w][l] = lo.v;
  }};

  loadDoc(0); writeStage(0); loadDoc(32);

  for (int n = 0; n < 16; ++n) {
    const int kk = n * 32;
    const int par = n & 1;

    asm volatile("s_waitcnt lgkmcnt(0)\n\ts_barrier" ::: "memory");

    const short8 ah0 = aH[par][0][l];
    const short8 ah1 = aH[par][1][l];
    const short8 al0 = aL[par][0][l];
    const short8 al1 = aL[par][1][l];

    short8 bh[2], bl[2];
#pragma unroll
    for (int ct = 0; ct < 2; ++ct) {
      const size_t off = (size_t)(cb + ct * 16 + lr) * 512 + kk + lg * 8;
      bh[ct] = *reinterpret_cast<const short8*>(Wt_hi + off);
      bl[ct] = *reinterpret_cast<const short8*>(Wt_lo + off);
    }

    if (n + 1 < 16) writeStage(par ^ 1);
    if (n + 2 < 16) loadDoc((n + 2) * 32);

#pragma unroll
    for (int ct = 0; ct < 2; ++ct) {
      acc[0][ct] = __builtin_amdgcn_mfma_f32_16x16x32_bf16(ah0, bh[ct], acc[0][ct], 0, 0, 0);
      acc[1][ct] = __builtin_amdgcn_mfma_f32_16x16x32_bf16(ah1, bh[ct], acc[1][ct], 0, 0, 0);
      acc[0][ct] = __builtin_amdgcn_mfma_f32_16x16x32_bf16(ah0, bl[ct], acc[0][ct], 0, 0, 0);
      acc[1][ct] = __builtin_amdgcn_mfma_f32_16x16x32_bf16(ah1, bl[ct], acc[1][ct], 0, 0, 0);
      acc[0][ct] = __builtin_amdgcn_mfma_f32_16x16x32_bf16(al0, bh[ct], acc[0][ct], 0, 0, 0);
      acc[1][ct] = __builtin_amdgcn_mfma_f32_16x16x32_bf16(al1, bh[ct], acc[1][ct], 0, 0, 0);
    }
  }

  float bias[2];
#pragma unroll
  for (int ct = 0; ct < 2; ++ct) bias[ct] = Wb[cb + ct * 16 + lr];
#pragma unroll
  for (int rt = 0; rt < 2; ++rt)
#pragma unroll
    for (int ct = 0; ct < 2; ++ct) {
#pragma unroll
      for (int q = 0; q < 4; ++q) acc[rt][ct][q] += bias[ct];
      ushort4v u;
#pragma unroll
      for (int q = 0; q < 4; ++q) u[q] = f2bf(acc[rt][ct][q]);
      *reinterpret_cast<ushort4v*>(
          ht + (size_t)(cb + ct * 16 + lr) * 8192 + rb + rt * 16 + lg * 4) = u;
    }

  float a1c[2], a2c[2];
#pragma unroll
  for (int ct = 0; ct < 2; ++ct) {
    a1c[ct] = a[cb + ct * 16 + lr];
    a2c[ct] = a[256 + cb + ct * 16 + lr];
  }
  float p1[2][4], p2[2][4];
#pragma unroll
  for (int rt = 0; rt < 2; ++rt)
#pragma unroll
    for (int q = 0; q < 4; ++q) {
      float x1 = 0.f, x2 = 0.f;
#pragma unroll
      for (int ct = 0; ct < 2; ++ct) {
        x1 = fmaf(acc[rt][ct][q], a1c[ct], x1);
        x2 = fmaf(acc[rt][ct][q], a2c[ct], x2);
      }
#pragma unroll
      for (int off = 1; off < 16; off <<= 1) {
        x1 += __shfl_xor(x1, off);
        x2 += __shfl_xor(x2, off);
      }
      p1[rt][q] = x1; p2[rt][q] = x2;
    }
  __syncthreads();
  if (lr == 0) {
#pragma unroll
    for (int rt = 0; rt < 2; ++rt)
#pragma unroll
      for (int q = 0; q < 4; ++q) {
        sred[w][0][rt * 16 + lg * 4 + q] = p1[rt][q];
        sred[w][1][rt * 16 + lg * 4 + q] = p2[rt][q];
      }
  }
  __syncthreads();
  if (t < 32) {
    float v1s = 0.f, v2s = 0.f;
#pragma unroll
    for (int ww = 0; ww < 8; ++ww) { v1s += sred[ww][0][t]; v2s += sred[ww][1][t]; }
    const int r = rb + t;
    s1[r] = v1s;
    e2[r] = __expf(v2s);
    e02[r] = __expf(SLOPE * v2s);
  }
}

// ---------------- K3: per-row Z -> rowinfo {E1*iz, E01*iz, T, iz} ----------------
__global__ __launch_bounds__(256) void k_z(
    const float* __restrict__ s1, const float* __restrict__ e2g,
    const float* __restrict__ e02g, const float* __restrict__ abp,
    float* __restrict__ rowinfo)
{
  __shared__ __align__(16) float es[8192];
  __shared__ __align__(16) float fs[8192];
  const int t = threadIdx.x;
  for (int i = t * 4; i < 8192; i += 1024) {
    *reinterpret_cast<f32x4*>(&es[i]) = *reinterpret_cast<const f32x4*>(e2g + i);
    *reinterpret_cast<f32x4*>(&fs[i]) = *reinterpret_cast<const f32x4*>(e02g + i);
  }
  __syncthreads();
  const int w = t >> 6, l = t & 63;
  const float ab = abp[0];
  const int rb = blockIdx.x * 16 + w * 4;
  float T[4], E1[4], E01[4];
#pragma unroll
  for (int rr = 0; rr < 4; ++rr) {
    const float s1a = s1[rb + rr] + ab;
    E1[rr] = __expf(s1a); E01[rr] = __expf(SLOPE * s1a); T[rr] = __expf(-s1a);
  }
  float zA[4] = {0.f,0.f,0.f,0.f}, zB[4] = {0.f,0.f,0.f,0.f};
  for (int i = l * 4; i < 8192; i += 256) {
    const f32x4 e = *reinterpret_cast<const f32x4*>(&es[i]);
    const f32x4 f = *reinterpret_cast<const f32x4*>(&fs[i]);
#pragma unroll
    for (int rr = 0; rr < 4; ++rr)
#pragma unroll
      for (int q = 0; q < 4; ++q) {
        const bool c = (e[q] >= T[rr]);
        zA[rr] += c ? e[q] : 0.f;
        zB[rr] += c ? 0.f : f[q];
      }
  }
#pragma unroll
  for (int rr = 0; rr < 4; ++rr) {
    float z = E1[rr] * zA[rr] + E01[rr] * zB[rr];
#pragma unroll
    for (int off = 32; off > 0; off >>= 1) z += __shfl_down(z, off);
    if (l == 0) {
      const float iz = 1.0f / z;
      f32x4 ri = (f32x4){E1[rr] * iz, E01[rr] * iz, T[rr], iz};
      *reinterpret_cast<f32x4*>(rowinfo + (size_t)(rb + rr) * 4) = ri;
    }
  }
}

// ---------------- K4: att + partial out via MFMA; gen2 = 256 B/row bursts ----------------
// grid (KS, 128), block 512 = 8 waves. 64 rows/block, 32-k windows.
// gen2 produces windows kw and kw+32 together: each row gets 2 back-to-back
// nt f32x4 stores covering 256 B contiguous. Frag LDS = 4 buffers (window m
// -> buf m&3); barrier cadence (1/window), B reg-prefetch, occupancy as r9.
__global__ __launch_bounds__(512, 4) void k_att(
    const float* __restrict__ rowinfo, const float* __restrict__ e2g,
    const float* __restrict__ e02g, const unsigned short* __restrict__ ht,
    float* __restrict__ att, float* __restrict__ part, int CHUNK)
{
  extern __shared__ __align__(16) char smem[];
  char* plsb  = smem;                                    // [4][4][64] short8 = 16 KB
  float* e2s  = reinterpret_cast<float*>(smem + 16384);  // CHUNK
  float* e02s = e2s + CHUNK;                             // CHUNK

  const int t = threadIdx.x, w = t >> 6, l = t & 63;
  const int lr = l & 15, lg = l >> 4;
  const int kbase = blockIdx.x * CHUNK;     // slice (fastest -> XCD)
  const int rb = blockIdx.y * 64;

  for (int i = t * 4; i < CHUNK; i += 2048) {
    *reinterpret_cast<f32x4*>(e2s + i)  = *reinterpret_cast<const f32x4*>(e2g + kbase + i);
    *reinterpret_cast<f32x4*>(e02s + i) = *reinterpret_cast<const f32x4*>(e02g + kbase + i);
  }

  const int r = l >> 3, jc = l & 7;
  const int rowW = rb + w * 8 + r;
  const f32x4 ri = *reinterpret_cast<const f32x4*>(rowinfo + (size_t)rowW * 4);
  const float E1z = ri[0], E01z = ri[1], T = ri[2];
  float* attW = att + (size_t)rowW * 8192 + kbase + jc * 4;
  const int fragoff = (w >> 1) * 1024 + ((jc >> 1) * 16 + (w & 1) * 8 + r) * 16 + (jc & 1) * 8;

  __syncthreads();

  // gen2: windows kw (-> buf pb0) and kw+32 (-> buf pb1); 256 B contiguous/row
  auto gen2 = [&](int kw, int pb0, int pb1) {
    const f32x4 eA = *reinterpret_cast<const f32x4*>(e2s + kw + jc * 4);
    const f32x4 fA = *reinterpret_cast<const f32x4*>(e02s + kw + jc * 4);
    const f32x4 eB = *reinterpret_cast<const f32x4*>(e2s + kw + 32 + jc * 4);
    const f32x4 fB = *reinterpret_cast<const f32x4*>(e02s + kw + 32 + jc * 4);
    f32x4 pA, pB;
#pragma unroll
    for (int q = 0; q < 4; ++q) {
      const bool cA = (eA[q] >= T);
      pA[q] = (cA ? E1z : E01z) * (cA ? eA[q] : fA[q]);
      const bool cB = (eB[q] >= T);
      pB[q] = (cB ? E1z : E01z) * (cB ? eB[q] : fB[q]);
    }
    __builtin_nontemporal_store(pA, reinterpret_cast<f32x4*>(attW + kw));
    __builtin_nontemporal_store(pB, reinterpret_cast<f32x4*>(attW + kw + 32));
    uint2 uA, uB;
    uA.x = cvt_pk_bf16(pA[0], pA[1]); uA.y = cvt_pk_bf16(pA[2], pA[3]);
    uB.x = cvt_pk_bf16(pB[0], pB[1]); uB.y = cvt_pk_bf16(pB[2], pB[3]);
    *reinterpret_cast<uint2*>(plsb + pb0 * 4096 + fragoff) = uA;
    *reinterpret_cast<uint2*>(plsb + pb1 * 4096 + fragoff) = uB;
  };

  const unsigned short* hbase = ht + (size_t)(w * 32 + lr) * 8192 + kbase + lg * 8;
  auto loadB = [&](short8* b, int n) {
    const int kk = n * 32;
    b[0] = *reinterpret_cast<const short8*>(hbase + kk);
    b[1] = *reinterpret_cast<const short8*>(hbase + kk + (size_t)16 * 8192);
  };

  f32x4 acc[4][2];
#pragma unroll
  for (int rt = 0; rt < 4; ++rt)
#pragma unroll
    for (int ct = 0; ct < 2; ++ct) acc[rt][ct] = (f32x4){0.f, 0.f, 0.f, 0.f};

  auto mma = [&](const short8* b, const short8& af0, const short8& af1,
                 const short8& af2, const short8& af3) {
    __builtin_amdgcn_s_setprio(1);
    acc[0][0] = __builtin_amdgcn_mfma_f32_16x16x32_bf16(af0, b[0], acc[0][0], 0, 0, 0);
    acc[1][0] = __builtin_amdgcn_mfma_f32_16x16x32_bf16(af1, b[0], acc[1][0], 0, 0, 0);
    acc[2][0] = __builtin_amdgcn_mfma_f32_16x16x32_bf16(af2, b[0], acc[2][0], 0, 0, 0);
    acc[3][0] = __builtin_amdgcn_mfma_f32_16x16x32_bf16(af3, b[0], acc[3][0], 0, 0, 0);
    acc[0][1] = __builtin_amdgcn_mfma_f32_16x16x32_bf16(af0, b[1], acc[0][1], 0, 0, 0);
    acc[1][1] = __builtin_amdgcn_mfma_f32_16x16x32_bf16(af1, b[1], acc[1][1], 0, 0, 0);
    acc[2][1] = __builtin_amdgcn_mfma_f32_16x16x32_bf16(af2, b[1], acc[2][1], 0, 0, 0);
    acc[3][1] = __builtin_amdgcn_mfma_f32_16x16x32_bf16(af3, b[1], acc[3][1], 0, 0, 0);
    __builtin_amdgcn_s_setprio(0);
  };

  short8 bAr[2], bBr[2];
  loadB(bAr, 0);            // b(0) issued before gen2(0)'s stores
  gen2(0, 0, 1);            // windows 0,1 -> bufs 0,1

  const int NIT = CHUNK / 32;   // even (64 at KS=4)
  for (int n = 0; n < NIT; n += 2) {
    loadB(bBr, n + 1);
    asm volatile("s_waitcnt lgkmcnt(0)\n\ts_barrier" ::: "memory");
    {
      const short8* pbuf = reinterpret_cast<const short8*>(plsb + (size_t)(n & 3) * 4096);
      const short8 af0 = pbuf[0 * 64 + l];
      const short8 af1 = pbuf[1 * 64 + l];
      const short8 af2 = pbuf[2 * 64 + l];
      const short8 af3 = pbuf[3 * 64 + l];
      if (n + 2 < NIT) gen2((n + 2) * 32, (n + 2) & 3, (n + 3) & 3);
      mma(bAr, af0, af1, af2, af3);
    }
    if (n + 2 < NIT) loadB(bAr, n + 2);
    asm volatile("s_waitcnt lgkmcnt(0)\n\ts_barrier" ::: "memory");
    {
      const short8* pbuf = reinterpret_cast<const short8*>(plsb + (size_t)((n + 1) & 3) * 4096);
      const short8 af0 = pbuf[0 * 64 + l];
      const short8 af1 = pbuf[1 * 64 + l];
      const short8 af2 = pbuf[2 * 64 + l];
      const short8 af3 = pbuf[3 * 64 + l];
      mma(bBr, af0, af1, af2, af3);
    }
  }

  float* pb = part + (size_t)blockIdx.x * ((size_t)NROW * DDIM);
#pragma unroll
  for (int rt = 0; rt < 4; ++rt)
#pragma unroll
    for (int ct = 0; ct < 2; ++ct)
#pragma unroll
      for (int q = 0; q < 4; ++q)
        __builtin_nontemporal_store(acc[rt][ct][q],
            pb + (size_t)(rb + rt * 16 + lg * 4 + q) * 256 + w * 32 + ct * 16 + lr);
}

// ---------------- K5: out = lrelu(sum_k part[k]) ----------------
__global__ __launch_bounds__(256) void k_reduce(
    const float* __restrict__ part, float* __restrict__ out, int KS)
{
  const size_t idx = ((size_t)blockIdx.x * 256 + threadIdx.x) * 4;
  f32x4 s = __builtin_nontemporal_load(reinterpret_cast<const f32x4*>(part + idx));
  for (int k = 1; k < KS; ++k) {
    const f32x4 v = __builtin_nontemporal_load(
        reinterpret_cast<const f32x4*>(part + (size_t)k * NROW * DDIM + idx));
#pragma unroll
    for (int q = 0; q < 4; ++q) s[q] += v[q];
  }
#pragma unroll
  for (int q = 0; q < 4; ++q) s[q] = lrelu(s[q]);
  __builtin_nontemporal_store(s, reinterpret_cast<f32x4*>(out + idx));
}

extern "C" void kernel_launch(void* const* d_in, const int* in_sizes, int n_in,
                              void* d_out, int out_size, void* d_ws, size_t ws_size,
                              hipStream_t stream)
{
  const float* doc = (const float*)d_in[0];
  const float* W   = (const float*)d_in[1];
  const float* Wb  = (const float*)d_in[2];
  const float* a   = (const float*)d_in[3];
  const float* ab  = (const float*)d_in[4];

  float* out = (float*)d_out;                 // 8192*256
  float* att = out + (size_t)8192 * 256;      // 8192*8192

  char* ws = (char*)d_ws;
  unsigned short* ht    = (unsigned short*)ws;                              // 4 MB
  unsigned short* Wt_hi = (unsigned short*)(ws + (size_t)4 * 1024 * 1024);  // 256 KB
  unsigned short* Wt_lo = Wt_hi + (size_t)256 * 512;                        // 256 KB
  float* s1      = (float*)(ws + (size_t)4 * 1024 * 1024 + 512 * 1024);     // 32 KB
  float* e2      = s1 + 8192;
  float* e02     = e2 + 8192;
  float* rowinfo = e02 + 8192;                                              // 128 KB
  const size_t base = (size_t)5 * 1024 * 1024;
  const size_t partBytes = (size_t)NROW * DDIM * sizeof(float);             // 8 MB

  int KS = 1;
  for (int c = 4; c >= 1; c >>= 1)
    if (base + (size_t)c * partBytes <= ws_size) { KS = c; break; }
  float* part = (float*)(ws + base);
  const int CHUNK = NROW / KS;
  const size_t smem = 16384 + (size_t)2 * CHUNK * sizeof(float);

  hipLaunchKernelGGL(k_prep,   dim3(128),     dim3(256), 0,    stream, W, Wt_hi, Wt_lo);
  hipLaunchKernelGGL(k_h,      dim3(256),     dim3(512), 0,    stream, doc, Wt_hi, Wt_lo, Wb, a, ht, s1, e2, e02);
  hipLaunchKernelGGL(k_z,      dim3(512),     dim3(256), 0,    stream, s1, e2, e02, ab, rowinfo);
  hipLaunchKernelGGL(k_att,    dim3(KS, 128), dim3(512), smem, stream, rowinfo, e2, e02, ht, att, part, CHUNK);
  hipLaunchKernelGGL(k_reduce, dim3(2048),    dim3(256), 0,    stream, part, out, KS);
}

// Round 17
// 126.814 us; speedup vs baseline: 2.5013x; 1.0108x over previous
//
#include <hip/hip_runtime.h>
#include <hip/hip_bf16.h>

// GAT layer — r16 structure (best: 128.2 us), single change vs r16:
// k_att visits its k-windows in a per-block ROTATED order (block y starts at
// pair ro=((y*29)%(NIT/2))*2, wraps mod NIT). Breaks the device-wide k-phase
// lockstep (all blocks writing the same 256-B column stripe at 32KB stride
// -> HBM channel hotspot) that is the remaining suspect for the 4.1 TB/s
// write cap (r14: no amplification, VALU 14%, MFMA 5%, 81% stall).

typedef __attribute__((ext_vector_type(4))) float f32x4;
typedef __attribute__((ext_vector_type(8))) short short8;
typedef __attribute__((ext_vector_type(4))) unsigned short ushort4v;

#define SLOPE 0.1f
#define NROW 8192
#define DDIM 256

__device__ __forceinline__ float lrelu(float x){ return fmaxf(x, SLOPE * x); }

__device__ __forceinline__ unsigned short f2bf(float f){
  union { float f; unsigned u; } v; v.f = f;
  unsigned r = (v.u + 0x7fffu + ((v.u >> 16) & 1u)) >> 16;
  return (unsigned short)r;
}
__device__ __forceinline__ float bf2f(unsigned short u){
  union { unsigned u; float f; } v; v.u = (unsigned)u << 16; return v.f;
}
__device__ __forceinline__ unsigned cvt_pk_bf16(float lo, float hi){
  unsigned r;
  asm("v_cvt_pk_bf16_f32 %0, %1, %2" : "=v"(r) : "v"(lo), "v"(hi));
  return r;
}

// ---------------- K0: Wt_hi/Wt_lo [256][512] bf16 split-transpose of W ----------------
__global__ __launch_bounds__(256) void k_prep(
    const float* __restrict__ W,
    unsigned short* __restrict__ Wt_hi, unsigned short* __restrict__ Wt_lo)
{
  const int tid = blockIdx.x * 256 + threadIdx.x;   // 32768 total
  const int c = tid >> 7, kq = tid & 127;
  ushort4v hi, lo;
#pragma unroll
  for (int j = 0; j < 4; ++j) {
    const float v = W[(size_t)(kq * 4 + j) * 256 + c];
    hi[j] = f2bf(v);
    lo[j] = f2bf(v - bf2f(hi[j]));
  }
  *reinterpret_cast<ushort4v*>(Wt_hi + (size_t)c * 512 + kq * 4) = hi;
  *reinterpret_cast<ushort4v*>(Wt_lo + (size_t)c * 512 + kq * 4) = lo;
}

// ---------------- K1: h-tile via split MFMA; fused s1/s2/e2/e02 + ht bf16 ----------------
__global__ __launch_bounds__(512, 2) void k_h(
    const float* __restrict__ doc, const unsigned short* __restrict__ Wt_hi,
    const unsigned short* __restrict__ Wt_lo, const float* __restrict__ Wb,
    const float* __restrict__ a,
    unsigned short* __restrict__ ht, float* __restrict__ s1,
    float* __restrict__ e2, float* __restrict__ e02)
{
  __shared__ __align__(16) short8 aH[2][2][64];
  __shared__ __align__(16) short8 aL[2][2][64];
  __shared__ float sred[8][2][32];

  const int t = threadIdx.x, w = t >> 6, l = t & 63;
  const int lr = l & 15, lg = l >> 4;
  const int rb = blockIdx.x * 32;
  const int cb = w * 32;

  f32x4 acc[2][2];
#pragma unroll
  for (int rt = 0; rt < 2; ++rt)
#pragma unroll
    for (int ct = 0; ct < 2; ++ct) acc[rt][ct] = (f32x4){0.f, 0.f, 0.f, 0.f};

  const float* docp = doc + (size_t)(rb + w * 16 + lr) * 512 + lg * 8;  // valid for w<2

  f32x4 v0, v1;
  auto loadDoc = [&](int k0) { if (w < 2) {
      v0 = *reinterpret_cast<const f32x4*>(docp + k0);
      v1 = *reinterpret_cast<const f32x4*>(docp + k0 + 4);
  }};
  auto writeStage = [&](int pb) { if (w < 2) {
      union { short8 v; unsigned short u[8]; } hi, lo;
#pragma unroll
      for (int q = 0; q < 4; ++q) {
        hi.u[q] = f2bf(v0[q]);     lo.u[q] = f2bf(v0[q] - bf2f(hi.u[q]));
        hi.u[4+q] = f2bf(v1[q]);   lo.u[4+q] = f2bf(v1[q] - bf2f(hi.u[4+q]));
      }
      aH[pb][w][l] = hi.v;
      aL[pb][w][l] = lo.v;
  }};

  loadDoc(0); writeStage(0); loadDoc(32);

  for (int n = 0; n < 16; ++n) {
    const int kk = n * 32;
    const int par = n & 1;

    asm volatile("s_waitcnt lgkmcnt(0)\n\ts_barrier" ::: "memory");

    const short8 ah0 = aH[par][0][l];
    const short8 ah1 = aH[par][1][l];
    const short8 al0 = aL[par][0][l];
    const short8 al1 = aL[par][1][l];

    short8 bh[2], bl[2];
#pragma unroll
    for (int ct = 0; ct < 2; ++ct) {
      const size_t off = (size_t)(cb + ct * 16 + lr) * 512 + kk + lg * 8;
      bh[ct] = *reinterpret_cast<const short8*>(Wt_hi + off);
      bl[ct] = *reinterpret_cast<const short8*>(Wt_lo + off);
    }

    if (n + 1 < 16) writeStage(par ^ 1);
    if (n + 2 < 16) loadDoc((n + 2) * 32);

#pragma unroll
    for (int ct = 0; ct < 2; ++ct) {
      acc[0][ct] = __builtin_amdgcn_mfma_f32_16x16x32_bf16(ah0, bh[ct], acc[0][ct], 0, 0, 0);
      acc[1][ct] = __builtin_amdgcn_mfma_f32_16x16x32_bf16(ah1, bh[ct], acc[1][ct], 0, 0, 0);
      acc[0][ct] = __builtin_amdgcn_mfma_f32_16x16x32_bf16(ah0, bl[ct], acc[0][ct], 0, 0, 0);
      acc[1][ct] = __builtin_amdgcn_mfma_f32_16x16x32_bf16(ah1, bl[ct], acc[1][ct], 0, 0, 0);
      acc[0][ct] = __builtin_amdgcn_mfma_f32_16x16x32_bf16(al0, bh[ct], acc[0][ct], 0, 0, 0);
      acc[1][ct] = __builtin_amdgcn_mfma_f32_16x16x32_bf16(al1, bh[ct], acc[1][ct], 0, 0, 0);
    }
  }

  float bias[2];
#pragma unroll
  for (int ct = 0; ct < 2; ++ct) bias[ct] = Wb[cb + ct * 16 + lr];
#pragma unroll
  for (int rt = 0; rt < 2; ++rt)
#pragma unroll
    for (int ct = 0; ct < 2; ++ct) {
#pragma unroll
      for (int q = 0; q < 4; ++q) acc[rt][ct][q] += bias[ct];
      ushort4v u;
#pragma unroll
      for (int q = 0; q < 4; ++q) u[q] = f2bf(acc[rt][ct][q]);
      *reinterpret_cast<ushort4v*>(
          ht + (size_t)(cb + ct * 16 + lr) * 8192 + rb + rt * 16 + lg * 4) = u;
    }

  float a1c[2], a2c[2];
#pragma unroll
  for (int ct = 0; ct < 2; ++ct) {
    a1c[ct] = a[cb + ct * 16 + lr];
    a2c[ct] = a[256 + cb + ct * 16 + lr];
  }
  float p1[2][4], p2[2][4];
#pragma unroll
  for (int rt = 0; rt < 2; ++rt)
#pragma unroll
    for (int q = 0; q < 4; ++q) {
      float x1 = 0.f, x2 = 0.f;
#pragma unroll
      for (int ct = 0; ct < 2; ++ct) {
        x1 = fmaf(acc[rt][ct][q], a1c[ct], x1);
        x2 = fmaf(acc[rt][ct][q], a2c[ct], x2);
      }
#pragma unroll
      for (int off = 1; off < 16; off <<= 1) {
        x1 += __shfl_xor(x1, off);
        x2 += __shfl_xor(x2, off);
      }
      p1[rt][q] = x1; p2[rt][q] = x2;
    }
  __syncthreads();
  if (lr == 0) {
#pragma unroll
    for (int rt = 0; rt < 2; ++rt)
#pragma unroll
      for (int q = 0; q < 4; ++q) {
        sred[w][0][rt * 16 + lg * 4 + q] = p1[rt][q];
        sred[w][1][rt * 16 + lg * 4 + q] = p2[rt][q];
      }
  }
  __syncthreads();
  if (t < 32) {
    float v1s = 0.f, v2s = 0.f;
#pragma unroll
    for (int ww = 0; ww < 8; ++ww) { v1s += sred[ww][0][t]; v2s += sred[ww][1][t]; }
    const int r = rb + t;
    s1[r] = v1s;
    e2[r] = __expf(v2s);
    e02[r] = __expf(SLOPE * v2s);
  }
}

// ---------------- K3: per-row Z -> rowinfo {E1*iz, E01*iz, T, iz} ----------------
__global__ __launch_bounds__(256) void k_z(
    const float* __restrict__ s1, const float* __restrict__ e2g,
    const float* __restrict__ e02g, const float* __restrict__ abp,
    float* __restrict__ rowinfo)
{
  __shared__ __align__(16) float es[8192];
  __shared__ __align__(16) float fs[8192];
  const int t = threadIdx.x;
  for (int i = t * 4; i < 8192; i += 1024) {
    *reinterpret_cast<f32x4*>(&es[i]) = *reinterpret_cast<const f32x4*>(e2g + i);
    *reinterpret_cast<f32x4*>(&fs[i]) = *reinterpret_cast<const f32x4*>(e02g + i);
  }
  __syncthreads();
  const int w = t >> 6, l = t & 63;
  const float ab = abp[0];
  const int rb = blockIdx.x * 16 + w * 4;
  float T[4], E1[4], E01[4];
#pragma unroll
  for (int rr = 0; rr < 4; ++rr) {
    const float s1a = s1[rb + rr] + ab;
    E1[rr] = __expf(s1a); E01[rr] = __expf(SLOPE * s1a); T[rr] = __expf(-s1a);
  }
  float zA[4] = {0.f,0.f,0.f,0.f}, zB[4] = {0.f,0.f,0.f,0.f};
  for (int i = l * 4; i < 8192; i += 256) {
    const f32x4 e = *reinterpret_cast<const f32x4*>(&es[i]);
    const f32x4 f = *reinterpret_cast<const f32x4*>(&fs[i]);
#pragma unroll
    for (int rr = 0; rr < 4; ++rr)
#pragma unroll
      for (int q = 0; q < 4; ++q) {
        const bool c = (e[q] >= T[rr]);
        zA[rr] += c ? e[q] : 0.f;
        zB[rr] += c ? 0.f : f[q];
      }
  }
#pragma unroll
  for (int rr = 0; rr < 4; ++rr) {
    float z = E1[rr] * zA[rr] + E01[rr] * zB[rr];
#pragma unroll
    for (int off = 32; off > 0; off >>= 1) z += __shfl_down(z, off);
    if (l == 0) {
      const float iz = 1.0f / z;
      f32x4 ri = (f32x4){E1[rr] * iz, E01[rr] * iz, T[rr], iz};
      *reinterpret_cast<f32x4*>(rowinfo + (size_t)(rb + rr) * 4) = ri;
    }
  }
}

// ---------------- K4: att + partial out via MFMA; gen2 bursts + rotated k-order ----------------
// grid (KS, 128), block 512 = 8 waves. 64 rows/block, 32-k windows, pairs.
// Per-block rotation ro decorrelates the k-phase across blocks (channel spread).
__global__ __launch_bounds__(512, 4) void k_att(
    const float* __restrict__ rowinfo, const float* __restrict__ e2g,
    const float* __restrict__ e02g, const unsigned short* __restrict__ ht,
    float* __restrict__ att, float* __restrict__ part, int CHUNK)
{
  extern __shared__ __align__(16) char smem[];
  char* plsb  = smem;                                    // [4][4][64] short8 = 16 KB
  float* e2s  = reinterpret_cast<float*>(smem + 16384);  // CHUNK
  float* e02s = e2s + CHUNK;                             // CHUNK

  const int t = threadIdx.x, w = t >> 6, l = t & 63;
  const int lr = l & 15, lg = l >> 4;
  const int kbase = blockIdx.x * CHUNK;     // slice (fastest -> XCD)
  const int rb = blockIdx.y * 64;

  for (int i = t * 4; i < CHUNK; i += 2048) {
    *reinterpret_cast<f32x4*>(e2s + i)  = *reinterpret_cast<const f32x4*>(e2g + kbase + i);
    *reinterpret_cast<f32x4*>(e02s + i) = *reinterpret_cast<const f32x4*>(e02g + kbase + i);
  }

  const int r = l >> 3, jc = l & 7;
  const int rowW = rb + w * 8 + r;
  const f32x4 ri = *reinterpret_cast<const f32x4*>(rowinfo + (size_t)rowW * 4);
  const float E1z = ri[0], E01z = ri[1], T = ri[2];
  float* attW = att + (size_t)rowW * 8192 + kbase + jc * 4;
  const int fragoff = (w >> 1) * 1024 + ((jc >> 1) * 16 + (w & 1) * 8 + r) * 16 + (jc & 1) * 8;

  __syncthreads();

  // gen2: windows kw, kw+32 (-> bufs pb0, pb1); 256 B contiguous per row
  auto gen2 = [&](int kw, int pb0, int pb1) {
    const f32x4 eA = *reinterpret_cast<const f32x4*>(e2s + kw + jc * 4);
    const f32x4 fA = *reinterpret_cast<const f32x4*>(e02s + kw + jc * 4);
    const f32x4 eB = *reinterpret_cast<const f32x4*>(e2s + kw + 32 + jc * 4);
    const f32x4 fB = *reinterpret_cast<const f32x4*>(e02s + kw + 32 + jc * 4);
    f32x4 pA, pB;
#pragma unroll
    for (int q = 0; q < 4; ++q) {
      const bool cA = (eA[q] >= T);
      pA[q] = (cA ? E1z : E01z) * (cA ? eA[q] : fA[q]);
      const bool cB = (eB[q] >= T);
      pB[q] = (cB ? E1z : E01z) * (cB ? eB[q] : fB[q]);
    }
    __builtin_nontemporal_store(pA, reinterpret_cast<f32x4*>(attW + kw));
    __builtin_nontemporal_store(pB, reinterpret_cast<f32x4*>(attW + kw + 32));
    uint2 uA, uB;
    uA.x = cvt_pk_bf16(pA[0], pA[1]); uA.y = cvt_pk_bf16(pA[2], pA[3]);
    uB.x = cvt_pk_bf16(pB[0], pB[1]); uB.y = cvt_pk_bf16(pB[2], pB[3]);
    *reinterpret_cast<uint2*>(plsb + pb0 * 4096 + fragoff) = uA;
    *reinterpret_cast<uint2*>(plsb + pb1 * 4096 + fragoff) = uB;
  };

  const unsigned short* hbase = ht + (size_t)(w * 32 + lr) * 8192 + kbase + lg * 8;
  auto loadB = [&](short8* b, int n) {
    const int kk = n * 32;
    b[0] = *reinterpret_cast<const short8*>(hbase + kk);
    b[1] = *reinterpret_cast<const short8*>(hbase + kk + (size_t)16 * 8192);
  };

  f32x4 acc[4][2];
#pragma unroll
  for (int rt = 0; rt < 4; ++rt)
#pragma unroll
    for (int ct = 0; ct < 2; ++ct) acc[rt][ct] = (f32x4){0.f, 0.f, 0.f, 0.f};

  auto mma = [&](const short8* b, const short8& af0, const short8& af1,
                 const short8& af2, const short8& af3) {
    __builtin_amdgcn_s_setprio(1);
    acc[0][0] = __builtin_amdgcn_mfma_f32_16x16x32_bf16(af0, b[0], acc[0][0], 0, 0, 0);
    acc[1][0] = __builtin_amdgcn_mfma_f32_16x16x32_bf16(af1, b[0], acc[1][0], 0, 0, 0);
    acc[2][0] = __builtin_amdgcn_mfma_f32_16x16x32_bf16(af2, b[0], acc[2][0], 0, 0, 0);
    acc[3][0] = __builtin_amdgcn_mfma_f32_16x16x32_bf16(af3, b[0], acc[3][0], 0, 0, 0);
    acc[0][1] = __builtin_amdgcn_mfma_f32_16x16x32_bf16(af0, b[1], acc[0][1], 0, 0, 0);
    acc[1][1] = __builtin_amdgcn_mfma_f32_16x16x32_bf16(af1, b[1], acc[1][1], 0, 0, 0);
    acc[2][1] = __builtin_amdgcn_mfma_f32_16x16x32_bf16(af2, b[1], acc[2][1], 0, 0, 0);
    acc[3][1] = __builtin_amdgcn_mfma_f32_16x16x32_bf16(af3, b[1], acc[3][1], 0, 0, 0);
    __builtin_amdgcn_s_setprio(0);
  };

  const int NIT = CHUNK / 32;                 // even (64 at KS=4)
  // per-block k-phase rotation (pair-aligned, wraps mod NIT)
  const int ro = ((blockIdx.y * 29) % (NIT / 2)) * 2;
  auto MW = [&](int n) { return (n + ro) % NIT; };

  short8 bAr[2], bBr[2];
  loadB(bAr, MW(0));                // b for first window, before its stores
  gen2(MW(0) * 32, 0, 1);           // windows MW(0), MW(0)+1 -> bufs 0,1

  for (int n = 0; n < NIT; n += 2) {
    loadB(bBr, MW(n + 1));
    asm volatile("s_waitcnt lgkmcnt(0)\n\ts_barrier" ::: "memory");
    {
      const short8* pbuf = reinterpret_cast<const short8*>(plsb + (size_t)(n & 3) * 4096);
      const short8 af0 = pbuf[0 * 64 + l];
      const short8 af1 = pbuf[1 * 64 + l];
      const short8 af2 = pbuf[2 * 64 + l];
      const short8 af3 = pbuf[3 * 64 + l];
      if (n + 2 < NIT) gen2(MW(n + 2) * 32, (n + 2) & 3, (n + 3) & 3);
      mma(bAr, af0, af1, af2, af3);
    }
    if (n + 2 < NIT) loadB(bAr, MW(n + 2));
    asm volatile("s_waitcnt lgkmcnt(0)\n\ts_barrier" ::: "memory");
    {
      const short8* pbuf = reinterpret_cast<const short8*>(plsb + (size_t)((n + 1) & 3) * 4096);
      const short8 af0 = pbuf[0 * 64 + l];
      const short8 af1 = pbuf[1 * 64 + l];
      const short8 af2 = pbuf[2 * 64 + l];
      const short8 af3 = pbuf[3 * 64 + l];
      mma(bBr, af0, af1, af2, af3);
    }
  }

  float* pb = part + (size_t)blockIdx.x * ((size_t)NROW * DDIM);
#pragma unroll
  for (int rt = 0; rt < 4; ++rt)
#pragma unroll
    for (int ct = 0; ct < 2; ++ct)
#pragma unroll
      for (int q = 0; q < 4; ++q)
        __builtin_nontemporal_store(acc[rt][ct][q],
            pb + (size_t)(rb + rt * 16 + lg * 4 + q) * 256 + w * 32 + ct * 16 + lr);
}

// ---------------- K5: out = lrelu(sum_k part[k]) ----------------
__global__ __launch_bounds__(256) void k_reduce(
    const float* __restrict__ part, float* __restrict__ out, int KS)
{
  const size_t idx = ((size_t)blockIdx.x * 256 + threadIdx.x) * 4;
  f32x4 s = __builtin_nontemporal_load(reinterpret_cast<const f32x4*>(part + idx));
  for (int k = 1; k < KS; ++k) {
    const f32x4 v = __builtin_nontemporal_load(
        reinterpret_cast<const f32x4*>(part + (size_t)k * NROW * DDIM + idx));
#pragma unroll
    for (int q = 0; q < 4; ++q) s[q] += v[q];
  }
#pragma unroll
  for (int q = 0; q < 4; ++q) s[q] = lrelu(s[q]);
  __builtin_nontemporal_store(s, reinterpret_cast<f32x4*>(out + idx));
}

extern "C" void kernel_launch(void* const* d_in, const int* in_sizes, int n_in,
                              void* d_out, int out_size, void* d_ws, size_t ws_size,
                              hipStream_t stream)
{
  const float* doc = (const float*)d_in[0];
  const float* W   = (const float*)d_in[1];
  const float* Wb  = (const float*)d_in[2];
  const float* a   = (const float*)d_in[3];
  const float* ab  = (const float*)d_in[4];

  float* out = (float*)d_out;                 // 8192*256
  float* att = out + (size_t)8192 * 256;      // 8192*8192

  char* ws = (char*)d_ws;
  unsigned short* ht    = (unsigned short*)ws;                              // 4 MB
  unsigned short* Wt_hi = (unsigned short*)(ws + (size_t)4 * 1024 * 1024);  // 256 KB
  unsigned short* Wt_lo = Wt_hi + (size_t)256 * 512;                        // 256 KB
  float* s1      = (float*)(ws + (size_t)4 * 1024 * 1024 + 512 * 1024);     // 32 KB
  float* e2      = s1 + 8192;
  float* e02     = e2 + 8192;
  float* rowinfo = e02 + 8192;                                              // 128 KB
  const size_t base = (size_t)5 * 1024 * 1024;
  const size_t partBytes = (size_t)NROW * DDIM * sizeof(float);             // 8 MB

  int KS = 1;
  for (int c = 4; c >= 1; c >>= 1)
    if (base + (size_t)c * partBytes <= ws_size) { KS = c; break; }
  float* part = (float*)(ws + base);
  const int CHUNK = NROW / KS;
  const size_t smem = 16384 + (size_t)2 * CHUNK * sizeof(float);

  hipLaunchKernelGGL(k_prep,   dim3(128),     dim3(256), 0,    stream, W, Wt_hi, Wt_lo);
  hipLaunchKernelGGL(k_h,      dim3(256),     dim3(512), 0,    stream, doc, Wt_hi, Wt_lo, Wb, a, ht, s1, e2, e02);
  hipLaunchKernelGGL(k_z,      dim3(512),     dim3(256), 0,    stream, s1, e2, e02, ab, rowinfo);
  hipLaunchKernelGGL(k_att,    dim3(KS, 128), dim3(512), smem, stream, rowinfo, e2, e02, ht, att, part, CHUNK);
  hipLaunchKernelGGL(k_reduce, dim3(2048),    dim3(256), 0,    stream, part, out, KS);
}